// Round 6
// baseline (192.777 us; speedup 1.0000x reference)
//
#include <hip/hip_runtime.h>
#include <math.h>

#define NA 49152      // 64*64*12 anchors
#define NB 16
#define ABLOCKS 192   // NA / 256
#define EPS 1e-3f     // decision-boundary guard; fast-sim error <= ~1e-4

typedef __attribute__((ext_vector_type(4))) float f4v;

__device__ __forceinline__ void nt_store4(float* p, float a, float b, float c, float d) {
  f4v v; v.x = a; v.y = b; v.z = c; v.w = d;
  __builtin_nontemporal_store(v, reinterpret_cast<f4v*>(p));
}

__constant__ float RP[21][2] = {
  {213.33335876464844f, 124.50563049316406f},
  {190.504638671875f,   115.11840057373047f},
  {169.9791717529297f,  101.77180480957031f},
  {146.72341918945312f, 96.25749206542969f},
  {128.86770629882812f, 87.2344970703125f},
  {150.34292602539062f, 101.61070251464844f},
  {119.29926300048828f, 98.73982238769531f},
  {100.03463745117188f, 99.74459838867188f},
  {82.62400817871094f,  101.2509536743164f},
  {148.91049194335938f, 112.71517181396484f},
  {114.37303161621094f, 113.20121002197266f},
  {91.90096282958984f,  116.49812316894531f},
  {74.75020599365234f,  119.37875366210938f},
  {149.59658813476562f, 124.09295654296875f},
  {119.72419738769531f, 126.36898040771484f},
  {99.59107208251953f,  129.40196228027344f},
  {82.82524108886719f,  131.584228515625f},
  {154.55911254882812f, 135.07681274414062f},
  {133.8833770751953f,  140.85983276367188f},
  {120.45906066894531f, 145.40306091308594f},
  {106.21541595458984f, 150.072265625f}
};

// numpy pairwise-sum (n=21) replica for REF_POSE.mean(axis=0)
__device__ __forceinline__ void ref_center(float& cx, float& cy) {
  #pragma clang fp contract(off)
  float rx[8], ry[8];
  #pragma unroll
  for (int j = 0; j < 8; ++j) {
    rx[j] = RP[j][0] + RP[j + 8][0];
    ry[j] = RP[j][1] + RP[j + 8][1];
  }
  float sx = ((rx[0] + rx[1]) + (rx[2] + rx[3])) + ((rx[4] + rx[5]) + (rx[6] + rx[7]));
  float sy = ((ry[0] + ry[1]) + (ry[2] + ry[3])) + ((ry[4] + ry[5]) + (ry[6] + ry[7]));
  #pragma unroll
  for (int j = 16; j < 21; ++j) { sx += RP[j][0]; sy += RP[j][1]; }
  cx = sx / 21.0f;
  cy = sy / 21.0f;
}

// base pose (block-invariant): c + s*(RP-c)@R. Rotations by 0/90/180/270 are
// exactly negate/swap under f32. Anchor = base + shift (same association as ref).
__device__ __forceinline__ float2 base_pt(int p, int j, float cx, float cy) {
  #pragma clang fp contract(off)
  const int si = p >> 2, oi = p & 3;
  const float s = (si == 0) ? 0.25f : (si == 1 ? 0.5f : 1.0f);
  const float dx = s * (RP[j][0] - cx);
  const float dy = s * (RP[j][1] - cy);
  const float rx = (oi == 0) ? dx : (oi == 1 ? -dy : (oi == 2 ? -dx : dy));
  const float ry = (oi == 0) ? dy : (oi == 1 ? dx : (oi == 2 ? -dy : -dx));
  return make_float2(cx + rx, cy + ry);
}

// flat float2-index f2 (anchor-local*21 + kpt) -> anchor coords from base table
__device__ __forceinline__ void dec_anchor(int f2, int a0, const float2* sb2,
                                           float& anx, float& any,
                                           int& aloc, int& j) {
  #pragma clang fp contract(off)
  aloc = f2 / 21;
  j = f2 - aloc * 21;
  const int a = a0 + aloc;
  const int p = a % 12;
  const int kc = a / 12;
  const float shx = 4.0f * (float)(kc & 63);
  const float shy = 4.0f * (float)(kc >> 6);
  const float2 bpv = sb2[p * 21 + j];
  anx = bpv.x + shx;
  any = bpv.y + shy;
}

// ============ Kernel A: decisions -> labels (carries the heavy fp64 path) ====
__global__ __launch_bounds__(256) void k_decide(const float* __restrict__ gt,
                                                const int* __restrict__ ht,
                                                float* __restrict__ ol) {
  __shared__ float2 sb2[252];     // base poses [p][j]
  __shared__ float2 sxy[42];      // gt xy [hand][j]
  __shared__ float svis[42];      // gt vis [hand][j]
  __shared__ float sden[2], srden[2], snv[2];
  __shared__ int sht[2];
  __shared__ int shsel[256];      // per-anchor decision code

  const int tid = threadIdx.x;
  const int b = blockIdx.x / ABLOCKS;
  const int ab = blockIdx.x % ABLOCKS;
  const int a0 = ab * 256;

  if (tid < 252) {
    float cx, cy; ref_center(cx, cy);
    sb2[tid] = base_pt(tid / 21, tid % 21, cx, cy);
  }
  if (tid < 42) {
    const int h = tid / 21, j = tid - h * 21;
    const float* g = gt + b * 126 + h * 63 + j * 3;
    sxy[tid] = make_float2(g[0], g[1]);
    svis[tid] = g[2];
  }
  if (tid == 252 || tid == 253) {   // per-hand area/denominator
    const int h = tid - 252;
    const float* g = gt + b * 126 + h * 63;
    float mnx = g[0], mxx = g[0], mny = g[1], mxy = g[1];
    float nv = (g[2] > 0.0f) ? 1.0f : 0.0f;
    for (int j = 1; j < 21; ++j) {
      float x = g[j * 3], y = g[j * 3 + 1];
      mnx = fminf(mnx, x); mxx = fmaxf(mxx, x);
      mny = fminf(mny, y); mxy = fmaxf(mxy, y);
      nv += (g[j * 3 + 2] > 0.0f) ? 1.0f : 0.0f;
    }
    const float area = (mxx - mnx) * (mxy - mny);
    const float s2 = fmaxf(area, 1.0f);
    const float den = (2.0f * s2) * 0.01f;   // 2*s2*k2, k2 -> 0.01f in f32
    sden[h] = den;
    srden[h] = -1.0f / den;
    snv[h] = fmaxf(nv, 1.0f);
  }
  if (tid == 254 || tid == 255) sht[tid - 254] = ht[b * 2 + (tid - 254)];
  __syncthreads();

  const int a = a0 + tid;
  const int p = a % 12;
  const int kc = a / 12;
  const float shx = 4.0f * (float)(kc & 63);
  const float shy = 4.0f * (float)(kc >> 6);
  const float2* bp = sb2 + p * 21;

  // ---- fast path: __expf-based sims ----
  const float rd0 = srden[0], rd1 = srden[1];
  bool inside = true;
  float s0f = 0.0f, s1f = 0.0f;
  #pragma unroll
  for (int j = 0; j < 21; ++j) {
    #pragma clang fp contract(off)
    const float anx = bp[j].x + shx;
    const float any = bp[j].y + shy;
    inside = inside && (anx >= 0.0f) && (any >= 0.0f) &&
                       (anx < 256.0f) && (any < 256.0f);
    const float2 g0 = sxy[j], g1 = sxy[21 + j];
    const float dx0 = anx - g0.x, dy0 = any - g0.y;
    const float dx1 = anx - g1.x, dy1 = any - g1.y;
    const float v0 = (svis[j] > 0.0f) ? 1.0f : 0.0f;
    const float v1 = (svis[21 + j] > 0.0f) ? 1.0f : 0.0f;
    s0f += __expf((dx0 * dx0 + dy0 * dy0) * rd0) * v0;
    s1f += __expf((dx1 * dx1 + dy1 * dy1) * rd1) * v1;
  }
  float sim0 = s0f / snv[0];
  float sim1 = s1f / snv[1];
  const float mxf = fmaxf(sim0, sim1);
  const bool need_exact = (fabsf(mxf - 0.5f) < EPS) ||
                          ((mxf > 0.5f - EPS) && (fabsf(sim0 - sim1) < EPS));

  if (need_exact) {
    // ---- exact fallback: bit-identical to round-1 (double exp, numpy tree) ----
    #pragma clang fp contract(off)
    float q0[8], q1[8];
    #pragma unroll
    for (int j = 0; j < 16; ++j) {
      const float ax = bp[j].x + shx, ay = bp[j].y + shy;
      const float2 g0 = sxy[j], g1 = sxy[21 + j];
      float dx0 = ax - g0.x, dy0 = ay - g0.y;
      float d20 = dx0 * dx0 + dy0 * dy0;
      float vv0 = (svis[j] > 0.0f) ? 1.0f : 0.0f;
      float t0 = (float)::exp((double)(-d20 / sden[0])) * vv0;
      float dx1 = ax - g1.x, dy1 = ay - g1.y;
      float d21 = dx1 * dx1 + dy1 * dy1;
      float vv1 = (svis[21 + j] > 0.0f) ? 1.0f : 0.0f;
      float t1 = (float)::exp((double)(-d21 / sden[1])) * vv1;
      if (j < 8) { q0[j] = t0; q1[j] = t1; }
      else       { q0[j - 8] += t0; q1[j - 8] += t1; }
    }
    float s0 = ((q0[0] + q0[1]) + (q0[2] + q0[3])) + ((q0[4] + q0[5]) + (q0[6] + q0[7]));
    float s1 = ((q1[0] + q1[1]) + (q1[2] + q1[3])) + ((q1[4] + q1[5]) + (q1[6] + q1[7]));
    #pragma unroll
    for (int j = 16; j < 21; ++j) {
      const float ax = bp[j].x + shx, ay = bp[j].y + shy;
      const float2 g0 = sxy[j], g1 = sxy[21 + j];
      float dx0 = ax - g0.x, dy0 = ay - g0.y;
      float d20 = dx0 * dx0 + dy0 * dy0;
      float vv0 = (svis[j] > 0.0f) ? 1.0f : 0.0f;
      s0 += (float)::exp((double)(-d20 / sden[0])) * vv0;
      float dx1 = ax - g1.x, dy1 = ay - g1.y;
      float d21 = dx1 * dx1 + dy1 * dy1;
      float vv1 = (svis[21 + j] > 0.0f) ? 1.0f : 0.0f;
      s1 += (float)::exp((double)(-d21 / sden[1])) * vv1;
    }
    sim0 = s0 / snv[0];
    sim1 = s1 / snv[1];
  }

  const int am = (sim1 > sim0) ? 1 : 0;   // argmax: first index wins ties
  const float mx = fmaxf(sim0, sim1);
  const bool pos = mx > 0.5f;
  const bool right = (am == 0) && pos && (sht[0] == 1) && inside;
  const bool left  = (am == 1) && pos && (sht[1] == 1) && inside;

  int c;            // -1 outside, 0 neg, 1 right, 2 left
  if (!inside)      c = -1;
  else if (right)   c = 1;
  else if (left)    c = 2;
  else              c = 0;
  shsel[tid] = c;
  __syncthreads();

  // ---- labels drain: 192 float4 per block, fully coalesced (NOT nontemporal:
  //      k_write re-reads these from L2) ----
  if (tid < 192) {
    float4* lf4 = reinterpret_cast<float4*>(ol + ((size_t)b * NA + a0) * 3);
    float r[4];
    #pragma unroll
    for (int k = 0; k < 4; ++k) {
      const int q = tid * 4 + k;
      const int al = q / 3;
      const int rr = q - al * 3;
      const int cc = shsel[al];
      float v;
      if (cc < 0)       v = -1.0f;
      else if (rr == 0) v = (cc == 2) ? 1.0f : 0.0f;   // left
      else if (rr == 1) v = (cc == 0) ? 1.0f : 0.0f;   // neg
      else              v = (cc == 1) ? 1.0f : 0.0f;   // right
      r[k] = v;
    }
    lf4[tid] = make_float4(r[0], r[1], r[2], r[3]);
  }
}

// ============ Kernel B: lean streamer (no fp64, no exp -> high occupancy) ====
__global__ __launch_bounds__(256) void k_write(const float* __restrict__ gt,
                                               const float* __restrict__ ol,
                                               float* __restrict__ oa,
                                               float* __restrict__ oins,
                                               float* __restrict__ oo) {
  __shared__ float2 sb2[252];     // base poses [p][j]
  __shared__ float2 stg[42];      // target xy [hand][j]
  __shared__ int scc[256];        // decision code: 0 neg, 1 right, 2 left, 255 outside

  const int tid = threadIdx.x;
  const int b = blockIdx.x / ABLOCKS;
  const int ab = blockIdx.x % ABLOCKS;
  const int a0 = ab * 256;

  if (tid < 252) {
    float cx, cy; ref_center(cx, cy);
    sb2[tid] = base_pt(tid / 21, tid % 21, cx, cy);
  }
  if (tid < 42) {
    const int h = tid / 21, j = tid - h * 21;
    const float* g = gt + b * 126 + h * 63 + j * 3;
    stg[tid] = make_float2(g[0], g[1]);
  }
  if (tid < 192) {   // decode one-hot labels back to codes (exactly one writer/anchor)
    const float4 lv = reinterpret_cast<const float4*>(ol + ((size_t)b * NA + a0) * 3)[tid];
    const float vv[4] = {lv.x, lv.y, lv.z, lv.w};
    #pragma unroll
    for (int k = 0; k < 4; ++k) {
      const int q = tid * 4 + k;
      const int al = q / 3;
      const int rr = q - al * 3;
      const float v = vv[k];
      if (rr == 0 && v == -1.0f) scc[al] = 255;       // outside
      else if (rr == 0 && v == 1.0f) scc[al] = 2;     // left
      else if (rr == 1 && v == 1.0f) scc[al] = 0;     // neg
      else if (rr == 2 && v == 1.0f) scc[al] = 1;     // right
    }
  }
  __syncthreads();

  // ---- offsets: 2688 float4 per block, fully coalesced, nontemporal ----
  {
    float* ob = oo + ((size_t)b * NA + a0) * 42;
    #pragma unroll
    for (int i = 0; i < 11; ++i) {
      #pragma clang fp contract(off)
      const int idx = i * 256 + tid;
      if (i == 10 && tid >= 128) break;
      float r[4];
      #pragma unroll
      for (int h = 0; h < 2; ++h) {
        float anx, any; int aloc, j;
        dec_anchor(idx * 2 + h, a0, sb2, anx, any, aloc, j);
        const int cc = scc[aloc];
        const bool has = (cc == 1) || (cc == 2);
        const int hoff = (cc == 2) ? 21 : 0;
        const float tx = has ? stg[hoff + j].x : 0.0f;
        const float ty = has ? stg[hoff + j].y : 0.0f;
        r[h * 2]     = (cc != 255) ? (tx - anx) : 0.0f;
        r[h * 2 + 1] = (cc != 255) ? (ty - any) : 0.0f;
      }
      nt_store4(ob + idx * 4, r[0], r[1], r[2], r[3]);
    }
  }

  // ---- anchors + inside (b == 0 blocks only), nontemporal ----
  if (b == 0) {
    float* ab4 = oa + (size_t)a0 * 42;
    #pragma unroll
    for (int i = 0; i < 11; ++i) {
      const int idx = i * 256 + tid;
      if (i == 10 && tid >= 128) break;
      float r[4];
      #pragma unroll
      for (int h = 0; h < 2; ++h) {
        float anx, any; int aloc, j;
        dec_anchor(idx * 2 + h, a0, sb2, anx, any, aloc, j);
        r[h * 2] = anx;
        r[h * 2 + 1] = any;
      }
      nt_store4(ab4 + idx * 4, r[0], r[1], r[2], r[3]);
    }
    if (tid < 64) {
      float* ib = oins + a0;
      nt_store4(ib + tid * 4,
                (scc[tid * 4]     != 255) ? 1.0f : 0.0f,
                (scc[tid * 4 + 1] != 255) ? 1.0f : 0.0f,
                (scc[tid * 4 + 2] != 255) ? 1.0f : 0.0f,
                (scc[tid * 4 + 3] != 255) ? 1.0f : 0.0f);
    }
  }
}

extern "C" void kernel_launch(void* const* d_in, const int* in_sizes, int n_in,
                              void* d_out, int out_size, void* d_ws, size_t ws_size,
                              hipStream_t stream) {
  (void)in_sizes; (void)n_in; (void)d_ws; (void)ws_size; (void)out_size;
  const float* gt = (const float*)d_in[0];   // (16,42,3) f32
  const int* ht = (const int*)d_in[1];       // (16,2) i32
  float* out = (float*)d_out;
  float* out_anchors = out;                                   // NA*42
  float* out_inside  = out + (size_t)NA * 42;                 // NA
  float* out_labels  = out + (size_t)NA * 43;                 // NB*NA*3
  float* out_offsets = out_labels + (size_t)NB * NA * 3;      // NB*NA*42

  hipLaunchKernelGGL(k_decide, dim3(NB * ABLOCKS), dim3(256), 0, stream,
                     gt, ht, out_labels);
  hipLaunchKernelGGL(k_write, dim3(NB * ABLOCKS), dim3(256), 0, stream,
                     gt, out_labels, out_anchors, out_inside, out_offsets);
}

// Round 7
// 164.543 us; speedup vs baseline: 1.1716x; 1.1716x over previous
//
#include <hip/hip_runtime.h>
#include <math.h>

#define NA 49152      // 64*64*12 anchors
#define NB 16
#define ABLOCKS 192   // NA / 256
#define EPS 1e-3f     // decision-boundary guard; fast-sim error <= ~1e-4

typedef __attribute__((ext_vector_type(4))) float f4v;

__device__ __forceinline__ void nt_store4(float* p, float a, float b, float c, float d) {
  f4v v; v.x = a; v.y = b; v.z = c; v.w = d;
  __builtin_nontemporal_store(v, reinterpret_cast<f4v*>(p));
}

__constant__ float RP[21][2] = {
  {213.33335876464844f, 124.50563049316406f},
  {190.504638671875f,   115.11840057373047f},
  {169.9791717529297f,  101.77180480957031f},
  {146.72341918945312f, 96.25749206542969f},
  {128.86770629882812f, 87.2344970703125f},
  {150.34292602539062f, 101.61070251464844f},
  {119.29926300048828f, 98.73982238769531f},
  {100.03463745117188f, 99.74459838867188f},
  {82.62400817871094f,  101.2509536743164f},
  {148.91049194335938f, 112.71517181396484f},
  {114.37303161621094f, 113.20121002197266f},
  {91.90096282958984f,  116.49812316894531f},
  {74.75020599365234f,  119.37875366210938f},
  {149.59658813476562f, 124.09295654296875f},
  {119.72419738769531f, 126.36898040771484f},
  {99.59107208251953f,  129.40196228027344f},
  {82.82524108886719f,  131.584228515625f},
  {154.55911254882812f, 135.07681274414062f},
  {133.8833770751953f,  140.85983276367188f},
  {120.45906066894531f, 145.40306091308594f},
  {106.21541595458984f, 150.072265625f}
};

// numpy pairwise-sum (n=21) replica for REF_POSE.mean(axis=0)
__device__ __forceinline__ void ref_center(float& cx, float& cy) {
  #pragma clang fp contract(off)
  float rx[8], ry[8];
  #pragma unroll
  for (int j = 0; j < 8; ++j) {
    rx[j] = RP[j][0] + RP[j + 8][0];
    ry[j] = RP[j][1] + RP[j + 8][1];
  }
  float sx = ((rx[0] + rx[1]) + (rx[2] + rx[3])) + ((rx[4] + rx[5]) + (rx[6] + rx[7]));
  float sy = ((ry[0] + ry[1]) + (ry[2] + ry[3])) + ((ry[4] + ry[5]) + (ry[6] + ry[7]));
  #pragma unroll
  for (int j = 16; j < 21; ++j) { sx += RP[j][0]; sy += RP[j][1]; }
  cx = sx / 21.0f;
  cy = sy / 21.0f;
}

// base pose (block-invariant): c + s*(RP-c)@R. Rotations by 0/90/180/270 are
// exactly negate/swap under f32. Anchor = base + shift (same association as ref).
__device__ __forceinline__ float2 base_pt(int p, int j, float cx, float cy) {
  #pragma clang fp contract(off)
  const int si = p >> 2, oi = p & 3;
  const float s = (si == 0) ? 0.25f : (si == 1 ? 0.5f : 1.0f);
  const float dx = s * (RP[j][0] - cx);
  const float dy = s * (RP[j][1] - cy);
  const float rx = (oi == 0) ? dx : (oi == 1 ? -dy : (oi == 2 ? -dx : dy));
  const float ry = (oi == 0) ? dy : (oi == 1 ? dx : (oi == 2 ? -dy : -dx));
  return make_float2(cx + rx, cy + ry);
}

__global__ __launch_bounds__(256, 5) void k_all(const float* __restrict__ gt,
                                                const int* __restrict__ ht,
                                                float* __restrict__ oa,
                                                float* __restrict__ oins,
                                                float* __restrict__ ol,
                                                float* __restrict__ oo) {
  __shared__ float2 sb2[252];     // base poses [p][j]
  __shared__ float4 sg4[21];      // gt xy packed: (x0,y0,x1,y1) per kpt
  __shared__ float2 sv2[21];      // vis as 0/1 floats (v0,v1) per kpt
  __shared__ float sden[2], srden[2], snv[2];
  __shared__ int sht[2];
  __shared__ float4 sanc[256];    // per-anchor (shx, shy, p*21 as float, 0)
  __shared__ int scc[256];        // decision code: -1 outside, 0 neg, 1 right, 2 left

  const int tid = threadIdx.x;
  const int b = blockIdx.x / ABLOCKS;
  const int ab = blockIdx.x % ABLOCKS;
  const int a0 = ab * 256;

  if (tid < 252) {
    float cx, cy; ref_center(cx, cy);
    sb2[tid] = base_pt(tid / 21, tid % 21, cx, cy);
  }
  if (tid < 21) {
    const float* g0 = gt + b * 126 + tid * 3;
    const float* g1 = g0 + 63;
    sg4[tid] = make_float4(g0[0], g0[1], g1[0], g1[1]);
    sv2[tid] = make_float2((g0[2] > 0.0f) ? 1.0f : 0.0f,
                           (g1[2] > 0.0f) ? 1.0f : 0.0f);
  }
  if (tid == 252 || tid == 253) {   // per-hand area/denominator
    const int h = tid - 252;
    const float* g = gt + b * 126 + h * 63;
    float mnx = g[0], mxx = g[0], mny = g[1], mxy = g[1];
    float nv = (g[2] > 0.0f) ? 1.0f : 0.0f;
    for (int j = 1; j < 21; ++j) {
      float x = g[j * 3], y = g[j * 3 + 1];
      mnx = fminf(mnx, x); mxx = fmaxf(mxx, x);
      mny = fminf(mny, y); mxy = fmaxf(mxy, y);
      nv += (g[j * 3 + 2] > 0.0f) ? 1.0f : 0.0f;
    }
    const float area = (mxx - mnx) * (mxy - mny);
    const float s2 = fmaxf(area, 1.0f);
    const float den = (2.0f * s2) * 0.01f;   // 2*s2*k2, k2 -> 0.01f in f32
    sden[h] = den;
    srden[h] = -1.0f / den;
    snv[h] = fmaxf(nv, 1.0f);
  }
  if (tid == 254 || tid == 255) sht[tid - 254] = ht[b * 2 + (tid - 254)];
  __syncthreads();

  const int a = a0 + tid;
  const int p = a % 12;
  const int kc = a / 12;
  const float shx = 4.0f * (float)(kc & 63);
  const float shy = 4.0f * (float)(kc >> 6);
  const int pb = p * 21;
  sanc[tid] = make_float4(shx, shy, (float)pb, 0.0f);

  // ---- fast path: __expf-based sims ----
  const float rd0 = srden[0], rd1 = srden[1];
  bool inside = true;
  float s0f = 0.0f, s1f = 0.0f;
  #pragma unroll
  for (int j = 0; j < 21; ++j) {
    #pragma clang fp contract(off)
    const float2 bpv = sb2[pb + j];
    const float anx = bpv.x + shx;
    const float any = bpv.y + shy;
    inside = inside && (anx >= 0.0f) && (any >= 0.0f) &&
                       (anx < 256.0f) && (any < 256.0f);
    const float4 g = sg4[j];
    const float2 v = sv2[j];
    const float dx0 = anx - g.x, dy0 = any - g.y;
    const float dx1 = anx - g.z, dy1 = any - g.w;
    s0f += __expf((dx0 * dx0 + dy0 * dy0) * rd0) * v.x;
    s1f += __expf((dx1 * dx1 + dy1 * dy1) * rd1) * v.y;
  }
  float sim0 = s0f / snv[0];
  float sim1 = s1f / snv[1];
  const float mxf = fmaxf(sim0, sim1);
  const bool need_exact = (fabsf(mxf - 0.5f) < EPS) ||
                          ((mxf > 0.5f - EPS) && (fabsf(sim0 - sim1) < EPS));

  if (__builtin_expect(need_exact, 0)) {
    // ---- exact fallback: bit-identical to round-1 (double exp, numpy tree) ----
    #pragma clang fp contract(off)
    float q0[8], q1[8];
    #pragma unroll
    for (int j = 0; j < 16; ++j) {
      const float2 bpv = sb2[pb + j];
      const float ax = bpv.x + shx, ay = bpv.y + shy;
      const float4 g = sg4[j];
      const float2 v = sv2[j];
      float dx0 = ax - g.x, dy0 = ay - g.y;
      float d20 = dx0 * dx0 + dy0 * dy0;
      float t0 = (float)::exp((double)(-d20 / sden[0])) * v.x;
      float dx1 = ax - g.z, dy1 = ay - g.w;
      float d21 = dx1 * dx1 + dy1 * dy1;
      float t1 = (float)::exp((double)(-d21 / sden[1])) * v.y;
      if (j < 8) { q0[j] = t0; q1[j] = t1; }
      else       { q0[j - 8] += t0; q1[j - 8] += t1; }
    }
    float s0 = ((q0[0] + q0[1]) + (q0[2] + q0[3])) + ((q0[4] + q0[5]) + (q0[6] + q0[7]));
    float s1 = ((q1[0] + q1[1]) + (q1[2] + q1[3])) + ((q1[4] + q1[5]) + (q1[6] + q1[7]));
    #pragma unroll
    for (int j = 16; j < 21; ++j) {
      const float2 bpv = sb2[pb + j];
      const float ax = bpv.x + shx, ay = bpv.y + shy;
      const float4 g = sg4[j];
      const float2 v = sv2[j];
      float dx0 = ax - g.x, dy0 = ay - g.y;
      float d20 = dx0 * dx0 + dy0 * dy0;
      s0 += (float)::exp((double)(-d20 / sden[0])) * v.x;
      float dx1 = ax - g.z, dy1 = ay - g.w;
      float d21 = dx1 * dx1 + dy1 * dy1;
      s1 += (float)::exp((double)(-d21 / sden[1])) * v.y;
    }
    sim0 = s0 / snv[0];
    sim1 = s1 / snv[1];
  }

  const int am = (sim1 > sim0) ? 1 : 0;   // argmax: first index wins ties
  const float mx = fmaxf(sim0, sim1);
  const bool pos = mx > 0.5f;
  const bool right = (am == 0) && pos && (sht[0] == 1) && inside;
  const bool left  = (am == 1) && pos && (sht[1] == 1) && inside;

  int c;            // -1 outside, 0 neg, 1 right, 2 left
  if (!inside)      c = -1;
  else if (right)   c = 1;
  else if (left)    c = 2;
  else              c = 0;
  scc[tid] = c;
  __syncthreads();

  // ---- labels: 192 NT float4 per block, fully coalesced ----
  if (tid < 192) {
    float* lb = ol + ((size_t)b * NA + a0) * 3;
    float r[4];
    #pragma unroll
    for (int k = 0; k < 4; ++k) {
      const int q = tid * 4 + k;
      const int al = q / 3;
      const int rr = q - al * 3;
      const int cc = scc[al];
      float v;
      if (cc < 0)       v = -1.0f;
      else if (rr == 0) v = (cc == 2) ? 1.0f : 0.0f;   // left
      else if (rr == 1) v = (cc == 0) ? 1.0f : 0.0f;   // neg
      else              v = (cc == 1) ? 1.0f : 0.0f;   // right
      r[k] = v;
    }
    nt_store4(lb + tid * 4, r[0], r[1], r[2], r[3]);
  }

  // ---- offsets: 2688 NT float4 per block; division-free (anchor,kpt) walk ----
  {
    float* ob = oo + ((size_t)b * NA + a0) * 42;
    int al = (2 * tid) / 21;            // one magic-div, then incremental
    int jj = 2 * tid - al * 21;
    #pragma unroll
    for (int i = 0; i < 11; ++i) {
      #pragma clang fp contract(off)
      if (i == 10 && tid >= 128) break;
      const int idx = i * 256 + tid;
      const bool w1 = (jj + 1) >= 21;   // elem1 = elem0 + 1
      const int al1 = al + (w1 ? 1 : 0);
      const int j1 = w1 ? 0 : (jj + 1);
      float r[4];
      {
        const float4 sa = sanc[al];
        const int cc = scc[al];
        const float2 bpv = sb2[(int)sa.z + jj];
        const float anx = bpv.x + sa.x, any = bpv.y + sa.y;
        const float4 g = sg4[jj];
        const bool has = (cc == 1) || (cc == 2);
        float tx = (cc == 2) ? g.z : g.x;
        float ty = (cc == 2) ? g.w : g.y;
        tx = has ? tx : 0.0f; ty = has ? ty : 0.0f;
        r[0] = (cc >= 0) ? (tx - anx) : 0.0f;
        r[1] = (cc >= 0) ? (ty - any) : 0.0f;
      }
      {
        const float4 sa = sanc[al1];
        const int cc = scc[al1];
        const float2 bpv = sb2[(int)sa.z + j1];
        const float anx = bpv.x + sa.x, any = bpv.y + sa.y;
        const float4 g = sg4[j1];
        const bool has = (cc == 1) || (cc == 2);
        float tx = (cc == 2) ? g.z : g.x;
        float ty = (cc == 2) ? g.w : g.y;
        tx = has ? tx : 0.0f; ty = has ? ty : 0.0f;
        r[2] = (cc >= 0) ? (tx - anx) : 0.0f;
        r[3] = (cc >= 0) ? (ty - any) : 0.0f;
      }
      nt_store4(ob + idx * 4, r[0], r[1], r[2], r[3]);
      jj += 8; al += 24;                 // advance by 512 elements
      if (jj >= 21) { jj -= 21; ++al; }
    }
  }

  // ---- anchors + inside (b == 0 blocks only) ----
  if (b == 0) {
    float* ap = oa + (size_t)a0 * 42;
    int al = (2 * tid) / 21;
    int jj = 2 * tid - al * 21;
    #pragma unroll
    for (int i = 0; i < 11; ++i) {
      if (i == 10 && tid >= 128) break;
      const int idx = i * 256 + tid;
      const bool w1 = (jj + 1) >= 21;
      const int al1 = al + (w1 ? 1 : 0);
      const int j1 = w1 ? 0 : (jj + 1);
      const float4 sa = sanc[al];
      const float2 bpv = sb2[(int)sa.z + jj];
      const float4 sb = sanc[al1];
      const float2 bq = sb2[(int)sb.z + j1];
      nt_store4(ap + idx * 4, bpv.x + sa.x, bpv.y + sa.y,
                              bq.x + sb.x,  bq.y + sb.y);
      jj += 8; al += 24;
      if (jj >= 21) { jj -= 21; ++al; }
    }
    if (tid < 64) {
      float* ib = oins + a0;
      nt_store4(ib + tid * 4,
                (scc[tid * 4]     >= 0) ? 1.0f : 0.0f,
                (scc[tid * 4 + 1] >= 0) ? 1.0f : 0.0f,
                (scc[tid * 4 + 2] >= 0) ? 1.0f : 0.0f,
                (scc[tid * 4 + 3] >= 0) ? 1.0f : 0.0f);
    }
  }
}

extern "C" void kernel_launch(void* const* d_in, const int* in_sizes, int n_in,
                              void* d_out, int out_size, void* d_ws, size_t ws_size,
                              hipStream_t stream) {
  (void)in_sizes; (void)n_in; (void)d_ws; (void)ws_size; (void)out_size;
  const float* gt = (const float*)d_in[0];   // (16,42,3) f32
  const int* ht = (const int*)d_in[1];       // (16,2) i32
  float* out = (float*)d_out;
  float* out_anchors = out;                                   // NA*42
  float* out_inside  = out + (size_t)NA * 42;                 // NA
  float* out_labels  = out + (size_t)NA * 43;                 // NB*NA*3
  float* out_offsets = out_labels + (size_t)NB * NA * 3;      // NB*NA*42

  hipLaunchKernelGGL(k_all, dim3(NB * ABLOCKS), dim3(256), 0, stream,
                     gt, ht, out_anchors, out_inside, out_labels, out_offsets);
}

// Round 8
// 159.853 us; speedup vs baseline: 1.2060x; 1.0293x over previous
//
#include <hip/hip_runtime.h>
#include <math.h>

#define NA 49152      // 64*64*12 anchors
#define NB 16
#define ABLOCKS 192   // NA / 256
#define EPS 1e-3f     // decision-boundary guard; fast-sim error <= ~1e-4

__device__ __forceinline__ void st4(float* p, float a, float b, float c, float d) {
  *reinterpret_cast<float4*>(p) = make_float4(a, b, c, d);
}

__constant__ float RP[21][2] = {
  {213.33335876464844f, 124.50563049316406f},
  {190.504638671875f,   115.11840057373047f},
  {169.9791717529297f,  101.77180480957031f},
  {146.72341918945312f, 96.25749206542969f},
  {128.86770629882812f, 87.2344970703125f},
  {150.34292602539062f, 101.61070251464844f},
  {119.29926300048828f, 98.73982238769531f},
  {100.03463745117188f, 99.74459838867188f},
  {82.62400817871094f,  101.2509536743164f},
  {148.91049194335938f, 112.71517181396484f},
  {114.37303161621094f, 113.20121002197266f},
  {91.90096282958984f,  116.49812316894531f},
  {74.75020599365234f,  119.37875366210938f},
  {149.59658813476562f, 124.09295654296875f},
  {119.72419738769531f, 126.36898040771484f},
  {99.59107208251953f,  129.40196228027344f},
  {82.82524108886719f,  131.584228515625f},
  {154.55911254882812f, 135.07681274414062f},
  {133.8833770751953f,  140.85983276367188f},
  {120.45906066894531f, 145.40306091308594f},
  {106.21541595458984f, 150.072265625f}
};

// numpy pairwise-sum (n=21) replica for REF_POSE.mean(axis=0)
__device__ __forceinline__ void ref_center(float& cx, float& cy) {
  #pragma clang fp contract(off)
  float rx[8], ry[8];
  #pragma unroll
  for (int j = 0; j < 8; ++j) {
    rx[j] = RP[j][0] + RP[j + 8][0];
    ry[j] = RP[j][1] + RP[j + 8][1];
  }
  float sx = ((rx[0] + rx[1]) + (rx[2] + rx[3])) + ((rx[4] + rx[5]) + (rx[6] + rx[7]));
  float sy = ((ry[0] + ry[1]) + (ry[2] + ry[3])) + ((ry[4] + ry[5]) + (ry[6] + ry[7]));
  #pragma unroll
  for (int j = 16; j < 21; ++j) { sx += RP[j][0]; sy += RP[j][1]; }
  cx = sx / 21.0f;
  cy = sy / 21.0f;
}

// base pose (block-invariant): c + s*(RP-c)@R. Rotations by 0/90/180/270 are
// exactly negate/swap under f32. Anchor = base + shift (same association as ref).
__device__ __forceinline__ float2 base_pt(int p, int j, float cx, float cy) {
  #pragma clang fp contract(off)
  const int si = p >> 2, oi = p & 3;
  const float s = (si == 0) ? 0.25f : (si == 1 ? 0.5f : 1.0f);
  const float dx = s * (RP[j][0] - cx);
  const float dy = s * (RP[j][1] - cy);
  const float rx = (oi == 0) ? dx : (oi == 1 ? -dy : (oi == 2 ? -dx : dy));
  const float ry = (oi == 0) ? dy : (oi == 1 ? dx : (oi == 2 ? -dy : -dx));
  return make_float2(cx + rx, cy + ry);
}

__global__ __launch_bounds__(256, 5) void k_all(const float* __restrict__ gt,
                                                const int* __restrict__ ht,
                                                float* __restrict__ oa,
                                                float* __restrict__ oins,
                                                float* __restrict__ ol,
                                                float* __restrict__ oo) {
  __shared__ float2 sb2[252];     // base poses [p][j]
  __shared__ float4 sg4[21];      // gt xy packed: (x0,y0,x1,y1) per kpt
  __shared__ float2 sv2[21];      // vis as 0/1 floats (v0,v1) per kpt
  __shared__ float sden[2], srden[2], snv[2];
  __shared__ int sht[2];
  __shared__ float4 sanc[256];    // per-anchor (shx, shy, p*21, decision code)

  const int tid = threadIdx.x;
  const int b = blockIdx.x / ABLOCKS;
  const int ab = blockIdx.x % ABLOCKS;
  const int a0 = ab * 256;

  if (tid < 252) {
    float cx, cy; ref_center(cx, cy);
    sb2[tid] = base_pt(tid / 21, tid % 21, cx, cy);
  }
  if (tid < 21) {
    const float* g0 = gt + b * 126 + tid * 3;
    const float* g1 = g0 + 63;
    sg4[tid] = make_float4(g0[0], g0[1], g1[0], g1[1]);
    sv2[tid] = make_float2((g0[2] > 0.0f) ? 1.0f : 0.0f,
                           (g1[2] > 0.0f) ? 1.0f : 0.0f);
  }
  if (tid == 252 || tid == 253) {   // per-hand area/denominator
    const int h = tid - 252;
    const float* g = gt + b * 126 + h * 63;
    float mnx = g[0], mxx = g[0], mny = g[1], mxy = g[1];
    float nv = (g[2] > 0.0f) ? 1.0f : 0.0f;
    for (int j = 1; j < 21; ++j) {
      float x = g[j * 3], y = g[j * 3 + 1];
      mnx = fminf(mnx, x); mxx = fmaxf(mxx, x);
      mny = fminf(mny, y); mxy = fmaxf(mxy, y);
      nv += (g[j * 3 + 2] > 0.0f) ? 1.0f : 0.0f;
    }
    const float area = (mxx - mnx) * (mxy - mny);
    const float s2 = fmaxf(area, 1.0f);
    const float den = (2.0f * s2) * 0.01f;   // 2*s2*k2, k2 -> 0.01f in f32
    sden[h] = den;
    srden[h] = -1.0f / den;
    snv[h] = fmaxf(nv, 1.0f);
  }
  if (tid == 254 || tid == 255) sht[tid - 254] = ht[b * 2 + (tid - 254)];
  __syncthreads();

  const int a = a0 + tid;
  const int p = a % 12;
  const int kc = a / 12;
  const float shx = 4.0f * (float)(kc & 63);
  const float shy = 4.0f * (float)(kc >> 6);
  const int pb = p * 21;

  // ---- fast path: __expf-based sims ----
  const float rd0 = srden[0], rd1 = srden[1];
  bool inside = true;
  float s0f = 0.0f, s1f = 0.0f;
  #pragma unroll
  for (int j = 0; j < 21; ++j) {
    #pragma clang fp contract(off)
    const float2 bpv = sb2[pb + j];
    const float anx = bpv.x + shx;
    const float any = bpv.y + shy;
    inside = inside && (anx >= 0.0f) && (any >= 0.0f) &&
                       (anx < 256.0f) && (any < 256.0f);
    const float4 g = sg4[j];
    const float2 v = sv2[j];
    const float dx0 = anx - g.x, dy0 = any - g.y;
    const float dx1 = anx - g.z, dy1 = any - g.w;
    s0f += __expf((dx0 * dx0 + dy0 * dy0) * rd0) * v.x;
    s1f += __expf((dx1 * dx1 + dy1 * dy1) * rd1) * v.y;
  }
  float sim0 = s0f / snv[0];
  float sim1 = s1f / snv[1];
  const float mxf = fmaxf(sim0, sim1);
  const bool need_exact = (fabsf(mxf - 0.5f) < EPS) ||
                          ((mxf > 0.5f - EPS) && (fabsf(sim0 - sim1) < EPS));

  if (__builtin_expect(need_exact, 0)) {
    // ---- exact fallback: bit-identical to round-1 (double exp, numpy tree) ----
    #pragma clang fp contract(off)
    float q0[8], q1[8];
    #pragma unroll
    for (int j = 0; j < 16; ++j) {
      const float2 bpv = sb2[pb + j];
      const float ax = bpv.x + shx, ay = bpv.y + shy;
      const float4 g = sg4[j];
      const float2 v = sv2[j];
      float dx0 = ax - g.x, dy0 = ay - g.y;
      float d20 = dx0 * dx0 + dy0 * dy0;
      float t0 = (float)::exp((double)(-d20 / sden[0])) * v.x;
      float dx1 = ax - g.z, dy1 = ay - g.w;
      float d21 = dx1 * dx1 + dy1 * dy1;
      float t1 = (float)::exp((double)(-d21 / sden[1])) * v.y;
      if (j < 8) { q0[j] = t0; q1[j] = t1; }
      else       { q0[j - 8] += t0; q1[j - 8] += t1; }
    }
    float s0 = ((q0[0] + q0[1]) + (q0[2] + q0[3])) + ((q0[4] + q0[5]) + (q0[6] + q0[7]));
    float s1 = ((q1[0] + q1[1]) + (q1[2] + q1[3])) + ((q1[4] + q1[5]) + (q1[6] + q1[7]));
    #pragma unroll
    for (int j = 16; j < 21; ++j) {
      const float2 bpv = sb2[pb + j];
      const float ax = bpv.x + shx, ay = bpv.y + shy;
      const float4 g = sg4[j];
      const float2 v = sv2[j];
      float dx0 = ax - g.x, dy0 = ay - g.y;
      float d20 = dx0 * dx0 + dy0 * dy0;
      s0 += (float)::exp((double)(-d20 / sden[0])) * v.x;
      float dx1 = ax - g.z, dy1 = ay - g.w;
      float d21 = dx1 * dx1 + dy1 * dy1;
      s1 += (float)::exp((double)(-d21 / sden[1])) * v.y;
    }
    sim0 = s0 / snv[0];
    sim1 = s1 / snv[1];
  }

  const int am = (sim1 > sim0) ? 1 : 0;   // argmax: first index wins ties
  const float mx = fmaxf(sim0, sim1);
  const bool pos = mx > 0.5f;
  const bool right = (am == 0) && pos && (sht[0] == 1) && inside;
  const bool left  = (am == 1) && pos && (sht[1] == 1) && inside;

  int c;            // -1 outside, 0 neg, 1 right, 2 left
  if (!inside)      c = -1;
  else if (right)   c = 1;
  else if (left)    c = 2;
  else              c = 0;
  sanc[tid] = make_float4(shx, shy, (float)pb, (float)c);   // code packed in .w
  __syncthreads();

  // ---- labels: 192 float4 per block, fully coalesced ----
  if (tid < 192) {
    float* lb = ol + ((size_t)b * NA + a0) * 3;
    float r[4];
    #pragma unroll
    for (int k = 0; k < 4; ++k) {
      const int q = tid * 4 + k;
      const int al = q / 3;
      const int rr = q - al * 3;
      const int cc = (int)sanc[al].w;
      float v;
      if (cc < 0)       v = -1.0f;
      else if (rr == 0) v = (cc == 2) ? 1.0f : 0.0f;   // left
      else if (rr == 1) v = (cc == 0) ? 1.0f : 0.0f;   // neg
      else              v = (cc == 1) ? 1.0f : 0.0f;   // right
      r[k] = v;
    }
    st4(lb + tid * 4, r[0], r[1], r[2], r[3]);
  }

  // ---- offsets: 2688 float4 per block; division-free (anchor,kpt) walk ----
  {
    float* ob = oo + ((size_t)b * NA + a0) * 42;
    int al = (2 * tid) / 21;            // one magic-div, then incremental
    int jj = 2 * tid - al * 21;
    #pragma unroll
    for (int i = 0; i < 11; ++i) {
      #pragma clang fp contract(off)
      if (i == 10 && tid >= 128) break;
      const int idx = i * 256 + tid;
      const bool w1 = (jj + 1) >= 21;   // elem1 = elem0 + 1
      const int al1 = al + (w1 ? 1 : 0);
      const int j1 = w1 ? 0 : (jj + 1);
      float r[4];
      {
        const float4 sa = sanc[al];
        const int cc = (int)sa.w;
        const float2 bpv = sb2[(int)sa.z + jj];
        const float anx = bpv.x + sa.x, any = bpv.y + sa.y;
        const float4 g = sg4[jj];
        const bool has = (cc == 1) || (cc == 2);
        float tx = (cc == 2) ? g.z : g.x;
        float ty = (cc == 2) ? g.w : g.y;
        tx = has ? tx : 0.0f; ty = has ? ty : 0.0f;
        r[0] = (cc >= 0) ? (tx - anx) : 0.0f;
        r[1] = (cc >= 0) ? (ty - any) : 0.0f;
      }
      {
        const float4 sa = sanc[al1];
        const int cc = (int)sa.w;
        const float2 bpv = sb2[(int)sa.z + j1];
        const float anx = bpv.x + sa.x, any = bpv.y + sa.y;
        const float4 g = sg4[j1];
        const bool has = (cc == 1) || (cc == 2);
        float tx = (cc == 2) ? g.z : g.x;
        float ty = (cc == 2) ? g.w : g.y;
        tx = has ? tx : 0.0f; ty = has ? ty : 0.0f;
        r[2] = (cc >= 0) ? (tx - anx) : 0.0f;
        r[3] = (cc >= 0) ? (ty - any) : 0.0f;
      }
      st4(ob + idx * 4, r[0], r[1], r[2], r[3]);
      jj += 8; al += 24;                 // advance by 512 elements
      if (jj >= 21) { jj -= 21; ++al; }
    }
  }

  // ---- anchors + inside: b-independent, distributed across all 16 b's ----
  // block (b,ab) writes float4 idx range [b*168, (b+1)*168) of its ab-chunk
  if (tid < 168) {
    float* ap = oa + (size_t)a0 * 42;
    const int idx = b * 168 + tid;
    const int e0 = idx * 2;
    const int al = e0 / 21;
    const int jj = e0 - al * 21;
    const bool w1 = (jj + 1) >= 21;
    const int al1 = al + (w1 ? 1 : 0);
    const int j1 = w1 ? 0 : (jj + 1);
    const float4 sa = sanc[al];
    const float2 bpv = sb2[(int)sa.z + jj];
    const float4 sb = sanc[al1];
    const float2 bq = sb2[(int)sb.z + j1];
    st4(ap + idx * 4, bpv.x + sa.x, bpv.y + sa.y,
                      bq.x + sb.x,  bq.y + sb.y);
  }
  if (tid < 4) {       // inside: 64 float4 per chunk, 4 per b (scc>=0 <=> inside, b-indep)
    const int t = b * 4 + tid;
    st4(oins + a0 + t * 4,
        (sanc[t * 4].w     >= 0.0f) ? 1.0f : 0.0f,
        (sanc[t * 4 + 1].w >= 0.0f) ? 1.0f : 0.0f,
        (sanc[t * 4 + 2].w >= 0.0f) ? 1.0f : 0.0f,
        (sanc[t * 4 + 3].w >= 0.0f) ? 1.0f : 0.0f);
  }
}

extern "C" void kernel_launch(void* const* d_in, const int* in_sizes, int n_in,
                              void* d_out, int out_size, void* d_ws, size_t ws_size,
                              hipStream_t stream) {
  (void)in_sizes; (void)n_in; (void)d_ws; (void)ws_size; (void)out_size;
  const float* gt = (const float*)d_in[0];   // (16,42,3) f32
  const int* ht = (const int*)d_in[1];       // (16,2) i32
  float* out = (float*)d_out;
  float* out_anchors = out;                                   // NA*42
  float* out_inside  = out + (size_t)NA * 42;                 // NA
  float* out_labels  = out + (size_t)NA * 43;                 // NB*NA*3
  float* out_offsets = out_labels + (size_t)NB * NA * 3;      // NB*NA*42

  hipLaunchKernelGGL(k_all, dim3(NB * ABLOCKS), dim3(256), 0, stream,
                     gt, ht, out_anchors, out_inside, out_labels, out_offsets);
}